// Round 1
// baseline (1098.160 us; speedup 1.0000x reference)
//
#include <hip/hip_runtime.h>
#include <math.h>

#define G 8
#define T 4096
#define H 1024
#define E 32
#define C 64
#define NTOK (G*T)                     // 32768 tokens
#define COMBINE_SZ ((size_t)G*T*E*C)   // 67108864 floats
#define KC 64                          // h-chunk size
#define TBLK 128                       // tokens per block (2 per lane)

// ---------------------------------------------------------------------------
// Kernel 1: router logits GEMM (fp32 vector) + softmax + z-loss + transposed
// probs store.  Grid: NTOK/128 = 256 blocks x 256 threads.
// Wave w (0..3) computes experts [8w,8w+8) for all 128 tokens; lane l holds
// tokens {l, 64+l} (2 per lane, 16 accumulators).
//
// R8: double-buffered LDS staging with T14 issue-early/write-late split.
// Global loads for chunk ch+1 are issued into registers BEFORE compute(ch)
// (HBM latency hides under the FMA+LDS compute phase); the LDS writes land
// after the post-compute barrier. FMA chain per (token,expert) is VERBATIM
// R2/R7 math, h-ascending — staging only changes WHERE the data sits.
// LDS: 2*34.8 + 2*8 + 16.9 = 100.5 KB (<160 KB/CU; 1 block/CU as before).
// ---------------------------------------------------------------------------
__global__ __launch_bounds__(256) void k_router(
    const float* __restrict__ x, const float* __restrict__ W,
    const float* __restrict__ bias, float* __restrict__ probs_t,
    float* __restrict__ z_out)
{
    __shared__ float xs[2][TBLK][68];  // 69.6 KB; row stride 68 floats (16B-aligned)
    __shared__ float ws2[2][KC][32];   // 16 KB
    __shared__ float lt[TBLK][33];     // 16.9 KB

    const int tid  = threadIdx.x;
    const int lane = tid & 63;
    const int wv   = __builtin_amdgcn_readfirstlane(tid >> 6);
    const int blk  = blockIdx.x;

    float acc0[8] = {0,0,0,0,0,0,0,0};   // token = blk*128 + lane
    float acc1[8] = {0,0,0,0,0,0,0,0};   // token = blk*128 + 64 + lane

    float4 wr0, wr1;     // W-chunk staging registers (2 float4 / thread)
    float4 xr[8];        // x-tile staging registers (8 float4 / thread)

    // ---- prologue: load chunk 0 into regs, write buf 0
    {
        const float4* __restrict__ src = (const float4*)(W);
        wr0 = src[tid];
        wr1 = src[tid + 256];
        #pragma unroll
        for (int k = 0; k < 8; ++k) {
            const int f   = k * 256 + tid;
            const int tok = f >> 4;
            const int h4  = f & 15;
            xr[k] = *(const float4*)(x + (size_t)(blk * TBLK + tok) * H + h4 * 4);
        }
    }
    {
        float4* __restrict__ dst = (float4*)ws2[0];
        dst[tid]       = wr0;
        dst[tid + 256] = wr1;
        #pragma unroll
        for (int k = 0; k < 8; ++k) {
            const int f   = k * 256 + tid;
            const int tok = f >> 4;
            const int h4  = f & 15;
            *(float4*)(&xs[0][tok][h4 * 4]) = xr[k];
        }
    }
    __syncthreads();

    for (int ch = 0; ch < H / KC; ++ch) {
        const int b = ch & 1;

        // ---- issue-early: global loads for chunk ch+1 into registers
        if (ch + 1 < H / KC) {
            const int h0n = (ch + 1) * KC;
            const float4* __restrict__ src = (const float4*)(W + (size_t)h0n * E);
            wr0 = src[tid];
            wr1 = src[tid + 256];
            #pragma unroll
            for (int k = 0; k < 8; ++k) {
                const int f   = k * 256 + tid;
                const int tok = f >> 4;
                const int h4  = f & 15;
                xr[k] = *(const float4*)(x + (size_t)(blk * TBLK + tok) * H + h0n + h4 * 4);
            }
        }

        // ---- compute: 2 tokens/lane x 8 experts (math verbatim)
        for (int hh = 0; hh < KC; hh += 4) {
            const float4 xa = *(const float4*)(&xs[b][lane][hh]);
            const float4 xb = *(const float4*)(&xs[b][64 + lane][hh]);
            #pragma unroll
            for (int j = 0; j < 4; ++j) {
                const float4 w0 = *(const float4*)(&ws2[b][hh + j][wv * 8]);
                const float4 w1 = *(const float4*)(&ws2[b][hh + j][wv * 8 + 4]);
                const float a_ = (j == 0) ? xa.x : (j == 1) ? xa.y : (j == 2) ? xa.z : xa.w;
                const float b_ = (j == 0) ? xb.x : (j == 1) ? xb.y : (j == 2) ? xb.z : xb.w;
                acc0[0] = fmaf(a_, w0.x, acc0[0]);  acc1[0] = fmaf(b_, w0.x, acc1[0]);
                acc0[1] = fmaf(a_, w0.y, acc0[1]);  acc1[1] = fmaf(b_, w0.y, acc1[1]);
                acc0[2] = fmaf(a_, w0.z, acc0[2]);  acc1[2] = fmaf(b_, w0.z, acc1[2]);
                acc0[3] = fmaf(a_, w0.w, acc0[3]);  acc1[3] = fmaf(b_, w0.w, acc1[3]);
                acc0[4] = fmaf(a_, w1.x, acc0[4]);  acc1[4] = fmaf(b_, w1.x, acc1[4]);
                acc0[5] = fmaf(a_, w1.y, acc0[5]);  acc1[5] = fmaf(b_, w1.y, acc1[5]);
                acc0[6] = fmaf(a_, w1.z, acc0[6]);  acc1[6] = fmaf(b_, w1.z, acc1[6]);
                acc0[7] = fmaf(a_, w1.w, acc0[7]);  acc1[7] = fmaf(b_, w1.w, acc1[7]);
            }
        }
        __syncthreads();

        // ---- write-late: registers -> other LDS buffer
        if (ch + 1 < H / KC) {
            const int bn = b ^ 1;
            float4* __restrict__ dst = (float4*)ws2[bn];
            dst[tid]       = wr0;
            dst[tid + 256] = wr1;
            #pragma unroll
            for (int k = 0; k < 8; ++k) {
                const int f   = k * 256 + tid;
                const int tok = f >> 4;
                const int h4  = f & 15;
                *(float4*)(&xs[bn][tok][h4 * 4]) = xr[k];
            }
            __syncthreads();
        }
    }

    #pragma unroll
    for (int e = 0; e < 8; ++e) {
        const float be = bias[wv * 8 + e];
        lt[lane][wv * 8 + e]      = acc0[e] + be;
        lt[64 + lane][wv * 8 + e] = acc1[e] + be;
    }
    __syncthreads();

    // softmax + z-loss: waves 0,1 — one token per lane (math verbatim R2)
    if (tid < TBLK) {
        float v[E];
        float m = -1e30f;
        #pragma unroll
        for (int e = 0; e < E; ++e) { v[e] = lt[tid][e]; m = fmaxf(m, v[e]); }
        float s = 0.f;
        #pragma unroll
        for (int e = 0; e < E; ++e) { v[e] = expf(v[e] - m); s += v[e]; }
        const float inv = 1.f / s;
        #pragma unroll
        for (int e = 0; e < E; ++e) lt[tid][e] = v[e] * inv;
        const float lz = m + logf(s);
        float zsq = lz * lz;
        #pragma unroll
        for (int off = 32; off; off >>= 1) zsq += __shfl_down(zsq, off, 64);
        if ((tid & 63) == 0) atomicAdd(z_out, zsq * (1.0f / (float)NTOK));
    }
    __syncthreads();

    // store probs transposed: probs_t[(g*E+e)*T + t], 128 tokens per block
    const int g  = blk >> 5;           // 32 blocks per group
    const int tb = (blk & 31) * TBLK;
    #pragma unroll
    for (int j = 0; j < 8; ++j) {
        const int e = wv * 8 + j;
        float* __restrict__ col = probs_t + ((size_t)(g * E + e)) * T + tb;
        col[lane]      = lt[lane][e];
        col[64 + lane] = lt[64 + lane][e];
    }
}

// ---------------------------------------------------------------------------
// Kernel 2 (R8 rewrite): per-(g,e) top-64, ONE sync-free wave per column.
// All 4096 keys register-resident: lane holds 64 mapped-u32 values (static
// indexing only), t = (j>>2)*256 + lane*4 + (j&3).  Hierarchical argmax:
// 8 group-maxes of 8 elements each; per round = 7 u64 compares + 6-level
// shfl_xor reduce + winner-lane group rebuild.  Key construction
// ((mapped<<32) | (4095-t)) and extraction order are IDENTICAL to the old
// block-level loop -> bit-exact jax.lax.top_k tie semantics (descending,
// ties -> lower index).  Gate is reconstructed by the exact bit-inverse of
// the monotone float->u32 mapping (same bits as probs_t[t]).
// No __syncthreads, no LDS, no cross-wave traffic.
// ---------------------------------------------------------------------------
__global__ __launch_bounds__(64) void k_topk(
    const float* __restrict__ probs_t, float* __restrict__ out)
{
    const int ge   = blockIdx.x;          // g*E + e
    const int g    = ge >> 5;
    const int e    = ge & 31;
    const int lane = threadIdx.x;         // 0..63, one wave
    const float* __restrict__ col = probs_t + (size_t)ge * T;

    // ---- load 64 values/lane (float4, fully coalesced: 1 KB per wave instr)
    unsigned v[64];
    #pragma unroll
    for (int j4 = 0; j4 < 16; ++j4) {
        const float4 p = *(const float4*)(col + j4 * 256 + lane * 4);
        {
            unsigned u = __float_as_uint(p.x);
            v[j4 * 4 + 0] = (u & 0x80000000u) ? ~u : (u | 0x80000000u);
        }
        {
            unsigned u = __float_as_uint(p.y);
            v[j4 * 4 + 1] = (u & 0x80000000u) ? ~u : (u | 0x80000000u);
        }
        {
            unsigned u = __float_as_uint(p.z);
            v[j4 * 4 + 2] = (u & 0x80000000u) ? ~u : (u | 0x80000000u);
        }
        {
            unsigned u = __float_as_uint(p.w);
            v[j4 * 4 + 3] = (u & 0x80000000u) ? ~u : (u | 0x80000000u);
        }
    }

    // ---- build 8 group maxes (u64 keys), groups of 8 elements
    unsigned long long gk[8];
    #pragma unroll
    for (int grp = 0; grp < 8; ++grp) {
        unsigned long long m = 0ull;
        #pragma unroll
        for (int q = 0; q < 8; ++q) {
            const int j = grp * 8 + q;
            const int t = ((j >> 2) << 8) + lane * 4 + (j & 3);
            const unsigned long long k =
                ((unsigned long long)v[j] << 32) | (unsigned)(4095 - t);
            m = (k > m) ? k : m;
        }
        gk[grp] = m;
    }

    // ---- 64 extraction rounds, no barriers
    for (int c = 0; c < C; ++c) {
        unsigned long long best = gk[0];
        #pragma unroll
        for (int grp = 1; grp < 8; ++grp) best = (gk[grp] > best) ? gk[grp] : best;
        #pragma unroll
        for (int off = 32; off; off >>= 1) {
            const unsigned long long o = __shfl_xor(best, off, 64);
            best = (o > best) ? o : best;
        }
        // best is wave-uniform; unique winner (t is unique in low bits)
        const int t = 4095 - (int)(best & 0xFFFFFFFFu);
        if (((t >> 2) & 63) == lane) {
            // exact inverse of the monotone mapping -> original float bits
            const unsigned mu   = (unsigned)(best >> 32);
            const unsigned orig = (mu & 0x80000000u) ? (mu & 0x7FFFFFFFu) : ~mu;
            const size_t idx = ((((size_t)g * T + t) * E + e) * C + c);
            out[idx] = __uint_as_float(orig);    // combine = gate
            out[idx + COMBINE_SZ] = 1.0f;        // dispatch mask
            const int jw = ((t >> 8) << 2) | (t & 3);   // element index in this lane
            const int gw = jw >> 3;                     // its group
            // rebuild only the affected group, zeroing the removed element
            #pragma unroll
            for (int grp = 0; grp < 8; ++grp) {
                if (grp == gw) {
                    unsigned long long m = 0ull;
                    #pragma unroll
                    for (int q = 0; q < 8; ++q) {
                        const int j = grp * 8 + q;
                        unsigned vv = v[j];
                        if (j == jw) { vv = 0u; v[j] = 0u; }
                        const int tq = ((j >> 2) << 8) + lane * 4 + (j & 3);
                        const unsigned long long k =
                            ((unsigned long long)vv << 32) | (unsigned)(4095 - tq);
                        m = (k > m) ? k : m;
                    }
                    gk[grp] = m;
                }
            }
        }
    }
}

// ---------------------------------------------------------------------------
extern "C" void kernel_launch(void* const* d_in, const int* in_sizes, int n_in,
                              void* d_out, int out_size, void* d_ws, size_t ws_size,
                              hipStream_t stream) {
    const float* x = (const float*)d_in[0];   // [G,T,H]
    const float* W = (const float*)d_in[1];   // [H,E]
    const float* b = (const float*)d_in[2];   // [E]
    float* out     = (float*)d_out;           // combine | dispatch | z_loss
    float* probs_t = (float*)d_ws;            // [G*E, T] = 4 MB scratch

    // outputs are one-hot-sparse; zero everything (incl. z_loss slot), then scatter
    hipMemsetAsync(d_out, 0, (size_t)out_size * sizeof(float), stream);

    k_router<<<NTOK / TBLK, 256, 0, stream>>>(x, W, b, probs_t, out + 2 * COMBINE_SZ);
    k_topk<<<G * E, 64, 0, stream>>>(probs_t, out);
}

// Round 2
// 822.014 us; speedup vs baseline: 1.3359x; 1.3359x over previous
//
#include <hip/hip_runtime.h>
#include <math.h>

#define G 8
#define T 4096
#define H 1024
#define E 32
#define C 64
#define NTOK (G*T)                     // 32768 tokens
#define COMBINE_SZ ((size_t)G*T*E*C)   // 67108864 floats
#define KC 64                          // h-chunk size
#define TBLK 128                       // tokens per block (2 per lane)

// ---------------------------------------------------------------------------
// Kernel 1: router logits GEMM (fp32 vector) + softmax + z-loss + transposed
// probs store.  Grid: NTOK/128 = 256 blocks x 256 threads.
// Wave w (0..3) computes experts [8w,8w+8) for all 128 tokens; lane l holds
// tokens {l, 64+l} (2 per lane, 16 accumulators).
//
// R9: revert R8 double-buffer (VGPR=256 -> scratch spills, 0.69GB phantom
// WRITE_SIZE, 495us).  Back to R7 single-buffer structure, PLUS: W is read
// via the SCALAR path (wave-uniform address -> s_load through constant
// cache) instead of LDS broadcast.  R6 showed the router is LDS-pipe bound
// with 8/10 ds_read_b128 per hh-block being W broadcasts; this removes them
// and the ws2 staging entirely.  LDS 51.7 KB -> 3 blocks/CU (12 waves).
// FMA chain per (token,expert) remains h-ascending, bit-identical W values
// -> math VERBATIM R2/R7 (absmax 0.0).
// ---------------------------------------------------------------------------
__global__ __launch_bounds__(256) void k_router(
    const float* __restrict__ x, const float* __restrict__ W,
    const float* __restrict__ bias, float* __restrict__ probs_t,
    float* __restrict__ z_out)
{
    __shared__ float xs[TBLK][68];  // 34.8 KB; row stride 68 floats (16B-aligned)
    __shared__ float lt[TBLK][33];  // 16.9 KB  (total 51.7 KB -> 3 blocks/CU)

    const int tid  = threadIdx.x;
    const int lane = tid & 63;
    const int wv   = __builtin_amdgcn_readfirstlane(tid >> 6);
    const int blk  = blockIdx.x;

    float acc0[8] = {0,0,0,0,0,0,0,0};   // token = blk*128 + lane
    float acc1[8] = {0,0,0,0,0,0,0,0};   // token = blk*128 + 64 + lane

    for (int ch = 0; ch < H / KC; ++ch) {
        const int h0 = ch * KC;

        // --- x tile: 128 tok x 64 h; f -> tok=f>>4, h4=f&15 (16 lanes cover a
        //     256 B contiguous row segment; 4 segments per wave-instr)
        #pragma unroll
        for (int k = 0; k < 8; ++k) {
            const int f   = k * 256 + tid;
            const int tok = f >> 4;
            const int h4  = f & 15;
            const float4 v = *(const float4*)(x + (size_t)(blk * TBLK + tok) * H + h0 + h4 * 4);
            *(float4*)(&xs[tok][h4 * 4]) = v;
        }
        __syncthreads();

        // --- compute: 2 tokens/lane x 8 experts; W via scalar loads
        //     (wave-uniform address: wv uniform, loop indices uniform)
        for (int hh = 0; hh < KC; hh += 4) {
            const float4 xa = *(const float4*)(&xs[lane][hh]);
            const float4 xb = *(const float4*)(&xs[64 + lane][hh]);
            #pragma unroll
            for (int j = 0; j < 4; ++j) {
                const float* __restrict__ wr = W + (size_t)(h0 + hh + j) * E + wv * 8;
                const float w0x = wr[0], w0y = wr[1], w0z = wr[2], w0w = wr[3];
                const float w1x = wr[4], w1y = wr[5], w1z = wr[6], w1w = wr[7];
                const float a_ = (j == 0) ? xa.x : (j == 1) ? xa.y : (j == 2) ? xa.z : xa.w;
                const float b_ = (j == 0) ? xb.x : (j == 1) ? xb.y : (j == 2) ? xb.z : xb.w;
                acc0[0] = fmaf(a_, w0x, acc0[0]);  acc1[0] = fmaf(b_, w0x, acc1[0]);
                acc0[1] = fmaf(a_, w0y, acc0[1]);  acc1[1] = fmaf(b_, w0y, acc1[1]);
                acc0[2] = fmaf(a_, w0z, acc0[2]);  acc1[2] = fmaf(b_, w0z, acc1[2]);
                acc0[3] = fmaf(a_, w0w, acc0[3]);  acc1[3] = fmaf(b_, w0w, acc1[3]);
                acc0[4] = fmaf(a_, w1x, acc0[4]);  acc1[4] = fmaf(b_, w1x, acc1[4]);
                acc0[5] = fmaf(a_, w1y, acc0[5]);  acc1[5] = fmaf(b_, w1y, acc1[5]);
                acc0[6] = fmaf(a_, w1z, acc0[6]);  acc1[6] = fmaf(b_, w1z, acc1[6]);
                acc0[7] = fmaf(a_, w1w, acc0[7]);  acc1[7] = fmaf(b_, w1w, acc1[7]);
            }
        }
        __syncthreads();
    }

    #pragma unroll
    for (int e = 0; e < 8; ++e) {
        const float be = bias[wv * 8 + e];
        lt[lane][wv * 8 + e]      = acc0[e] + be;
        lt[64 + lane][wv * 8 + e] = acc1[e] + be;
    }
    __syncthreads();

    // softmax + z-loss: waves 0,1 — one token per lane (math verbatim R2)
    if (tid < TBLK) {
        float v[E];
        float m = -1e30f;
        #pragma unroll
        for (int e = 0; e < E; ++e) { v[e] = lt[tid][e]; m = fmaxf(m, v[e]); }
        float s = 0.f;
        #pragma unroll
        for (int e = 0; e < E; ++e) { v[e] = expf(v[e] - m); s += v[e]; }
        const float inv = 1.f / s;
        #pragma unroll
        for (int e = 0; e < E; ++e) lt[tid][e] = v[e] * inv;
        const float lz = m + logf(s);
        float zsq = lz * lz;
        #pragma unroll
        for (int off = 32; off; off >>= 1) zsq += __shfl_down(zsq, off, 64);
        // same 64-token partial groups + same shfl tree as R2/R6; 512 atomics total
        if ((tid & 63) == 0) atomicAdd(z_out, zsq * (1.0f / (float)NTOK));
    }
    __syncthreads();

    // store probs transposed: probs_t[(g*E+e)*T + t], 128 tokens per block
    const int g  = blk >> 5;           // 32 blocks per group
    const int tb = (blk & 31) * TBLK;
    #pragma unroll
    for (int j = 0; j < 8; ++j) {
        const int e = wv * 8 + j;
        float* __restrict__ col = probs_t + ((size_t)(g * E + e)) * T + tb;
        col[lane]      = lt[lane][e];
        col[64 + lane] = lt[64 + lane][e];
    }
}

// ---------------------------------------------------------------------------
// Kernel 2: per-(g,e) top-64 with exact jax.lax.top_k tie semantics
// (descending, ties -> lower index); scatter into zeroed combine/dispatch.
// Verbatim R2/R0 block version (known-good).  Will surface in top-5 now that
// the fill is small -> full counters for a targeted redesign next round.
// ---------------------------------------------------------------------------
__global__ __launch_bounds__(256) void k_topk(
    const float* __restrict__ probs_t, float* __restrict__ out)
{
    const int ge  = blockIdx.x;          // g*E + e
    const int g   = ge >> 5;
    const int e   = ge & 31;
    const int tid = threadIdx.x;
    const float* __restrict__ col = probs_t + (size_t)ge * T;

    float vals[16];
    unsigned long long keys[16];
    #pragma unroll
    for (int j = 0; j < 16; ++j) {
        const int t = j * 256 + tid;
        const float p = col[t];
        unsigned u = __float_as_uint(p);
        u = (u & 0x80000000u) ? ~u : (u | 0x80000000u);
        keys[j] = ((unsigned long long)u << 32) | (unsigned)(4095 - t);
        vals[j] = p;
    }

    __shared__ unsigned long long wmax[4];
    __shared__ unsigned long long gk;

    for (int c = 0; c < C; ++c) {
        unsigned long long kmax = 0ull;
        #pragma unroll
        for (int j = 0; j < 16; ++j) kmax = (keys[j] > kmax) ? keys[j] : kmax;
        #pragma unroll
        for (int off = 32; off; off >>= 1) {
            const unsigned long long o = __shfl_xor(kmax, off, 64);
            kmax = (o > kmax) ? o : kmax;
        }
        if ((tid & 63) == 0) wmax[tid >> 6] = kmax;
        __syncthreads();
        if (tid == 0) {
            unsigned long long m = wmax[0];
            #pragma unroll
            for (int w = 1; w < 4; ++w) m = (wmax[w] > m) ? wmax[w] : m;
            gk = m;
        }
        __syncthreads();
        const unsigned long long gkey = gk;
        #pragma unroll
        for (int j = 0; j < 16; ++j) {
            if (keys[j] == gkey) {   // unique winner
                const int t = 4095 - (int)(gkey & 0xFFFFFFFFu);
                const size_t idx = ((((size_t)g * T + t) * E + e) * C + c);
                out[idx] = vals[j];                 // combine = gate
                out[idx + COMBINE_SZ] = 1.0f;       // dispatch mask
                keys[j] = 0ull;
            }
        }
    }
}

// ---------------------------------------------------------------------------
extern "C" void kernel_launch(void* const* d_in, const int* in_sizes, int n_in,
                              void* d_out, int out_size, void* d_ws, size_t ws_size,
                              hipStream_t stream) {
    const float* x = (const float*)d_in[0];   // [G,T,H]
    const float* W = (const float*)d_in[1];   // [H,E]
    const float* b = (const float*)d_in[2];   // [E]
    float* out     = (float*)d_out;           // combine | dispatch | z_loss
    float* probs_t = (float*)d_ws;            // [G*E, T] = 4 MB scratch

    // R9 FIX: zero exactly the real output region — (2*COMBINE_SZ+1) floats =
    // 536,870,916 bytes.  R1 counters proved the old `out_size*sizeof(float)`
    // memset wrote 2.147 GB (4x the output: out_size is in BYTES), costing
    // 345us at the write ceiling instead of ~87us.
    hipMemsetAsync(d_out, 0, (size_t)(2 * COMBINE_SZ + 1) * sizeof(float), stream);

    k_router<<<NTOK / TBLK, 256, 0, stream>>>(x, W, b, probs_t, out + 2 * COMBINE_SZ);
    k_topk<<<G * E, 256, 0, stream>>>(probs_t, out);
}

// Round 3
// 685.653 us; speedup vs baseline: 1.6016x; 1.1989x over previous
//
#include <hip/hip_runtime.h>
#include <math.h>

#define G 8
#define T 4096
#define H 1024
#define E 32
#define C 64
#define NTOK (G*T)                     // 32768 tokens
#define COMBINE_SZ ((size_t)G*T*E*C)   // 67108864 floats
#define KC 64                          // h-chunk size
#define TBLK 128                       // tokens per block (2 per lane)

// ---------------------------------------------------------------------------
// Kernel 1: router logits GEMM (fp32 vector) + softmax + z-loss + transposed
// probs store.  VERBATIM R7 (the 693us-era router, ~115us): LDS-staged W+x,
// 2 tokens/lane x 8 experts/wave.  R9's scalar-W variant regressed (dependent
// s_load->FMA chain, no prefetch distance) and is reverted.
// ---------------------------------------------------------------------------
__global__ __launch_bounds__(256) void k_router(
    const float* __restrict__ x, const float* __restrict__ W,
    const float* __restrict__ bias, float* __restrict__ probs_t,
    float* __restrict__ z_out)
{
    __shared__ float xs[TBLK][68];  // 34.8 KB; row stride 68 floats (16B-aligned)
    __shared__ float ws2[KC][32];   // 8 KB
    __shared__ float lt[TBLK][33];  // 16.9 KB  (total 59.9 KB)

    const int tid  = threadIdx.x;
    const int lane = tid & 63;
    const int wv   = __builtin_amdgcn_readfirstlane(tid >> 6);
    const int blk  = blockIdx.x;

    float acc0[8] = {0,0,0,0,0,0,0,0};   // token = blk*128 + lane
    float acc1[8] = {0,0,0,0,0,0,0,0};   // token = blk*128 + 64 + lane

    for (int ch = 0; ch < H / KC; ++ch) {
        const int h0 = ch * KC;

        // --- W chunk: 64 h x 32 e = 8 KB, contiguous, coalesced
        {
            const float4* __restrict__ src = (const float4*)(W + (size_t)h0 * E);
            float4* __restrict__ dst = (float4*)ws2;
            dst[tid]       = src[tid];
            dst[tid + 256] = src[tid + 256];
        }
        // --- x tile: 128 tok x 64 h; f -> tok=f>>4, h4=f&15
        #pragma unroll
        for (int k = 0; k < 8; ++k) {
            const int f   = k * 256 + tid;
            const int tok = f >> 4;
            const int h4  = f & 15;
            const float4 v = *(const float4*)(x + (size_t)(blk * TBLK + tok) * H + h0 + h4 * 4);
            *(float4*)(&xs[tok][h4 * 4]) = v;
        }
        __syncthreads();

        // --- compute: 2 tokens/lane x 8 experts
        for (int hh = 0; hh < KC; hh += 4) {
            const float4 xa = *(const float4*)(&xs[lane][hh]);
            const float4 xb = *(const float4*)(&xs[64 + lane][hh]);
            #pragma unroll
            for (int j = 0; j < 4; ++j) {
                const float4 w0 = *(const float4*)(&ws2[hh + j][wv * 8]);
                const float4 w1 = *(const float4*)(&ws2[hh + j][wv * 8 + 4]);
                const float a_ = (j == 0) ? xa.x : (j == 1) ? xa.y : (j == 2) ? xa.z : xa.w;
                const float b_ = (j == 0) ? xb.x : (j == 1) ? xb.y : (j == 2) ? xb.z : xb.w;
                acc0[0] = fmaf(a_, w0.x, acc0[0]);  acc1[0] = fmaf(b_, w0.x, acc1[0]);
                acc0[1] = fmaf(a_, w0.y, acc0[1]);  acc1[1] = fmaf(b_, w0.y, acc1[1]);
                acc0[2] = fmaf(a_, w0.z, acc0[2]);  acc1[2] = fmaf(b_, w0.z, acc1[2]);
                acc0[3] = fmaf(a_, w0.w, acc0[3]);  acc1[3] = fmaf(b_, w0.w, acc1[3]);
                acc0[4] = fmaf(a_, w1.x, acc0[4]);  acc1[4] = fmaf(b_, w1.x, acc1[4]);
                acc0[5] = fmaf(a_, w1.y, acc0[5]);  acc1[5] = fmaf(b_, w1.y, acc1[5]);
                acc0[6] = fmaf(a_, w1.z, acc0[6]);  acc1[6] = fmaf(b_, w1.z, acc1[6]);
                acc0[7] = fmaf(a_, w1.w, acc0[7]);  acc1[7] = fmaf(b_, w1.w, acc1[7]);
            }
        }
        __syncthreads();
    }

    #pragma unroll
    for (int e = 0; e < 8; ++e) {
        const float be = bias[wv * 8 + e];
        lt[lane][wv * 8 + e]      = acc0[e] + be;
        lt[64 + lane][wv * 8 + e] = acc1[e] + be;
    }
    __syncthreads();

    // softmax + z-loss: waves 0,1 — one token per lane (math verbatim R2)
    if (tid < TBLK) {
        float v[E];
        float m = -1e30f;
        #pragma unroll
        for (int e = 0; e < E; ++e) { v[e] = lt[tid][e]; m = fmaxf(m, v[e]); }
        float s = 0.f;
        #pragma unroll
        for (int e = 0; e < E; ++e) { v[e] = expf(v[e] - m); s += v[e]; }
        const float inv = 1.f / s;
        #pragma unroll
        for (int e = 0; e < E; ++e) lt[tid][e] = v[e] * inv;
        const float lz = m + logf(s);
        float zsq = lz * lz;
        #pragma unroll
        for (int off = 32; off; off >>= 1) zsq += __shfl_down(zsq, off, 64);
        if ((tid & 63) == 0) atomicAdd(z_out, zsq * (1.0f / (float)NTOK));
    }
    __syncthreads();

    // store probs transposed: probs_t[(g*E+e)*T + t], 128 tokens per block
    const int g  = blk >> 5;           // 32 blocks per group
    const int tb = (blk & 31) * TBLK;
    #pragma unroll
    for (int j = 0; j < 8; ++j) {
        const int e = wv * 8 + j;
        float* __restrict__ col = probs_t + ((size_t)(g * E + e)) * T + tb;
        col[lane]      = lt[lane][e];
        col[64 + lane] = lt[64 + lane][e];
    }
}

// ---------------------------------------------------------------------------
// Kernel 2 (R10 rewrite): per-(g,e) top-64 WITHOUT the 64-round serial chain.
//
//   1. thr = min over 64 group-max keys (groups of 4 threads = 64 elements
//      each).  The 64 group maxima are 64 distinct keys all >= thr, so the
//      64th-largest key >= thr -> every top-64 key survives `key >= thr`.
//      Expected survivors ~280 on random data (exact at any count).
//   2. Ballot-compact survivors into LDS (1 atomic per wave per pass).
//   3. rank(x) = #{survivors > x}.  For x in top-64, all greater keys are
//      also top-64 (subset of survivors) -> in-set rank == global rank.
//      Keys unique (index in low bits) -> no ties; key order ==
//      jax.lax.top_k order (descending value, ties -> lower index).
//      Winners (rank < 64) scatter at c = rank.
// Gate decode (bit-inverse of the monotone map) harness-proven in R1
// (absmax 0.0).  No serial rounds: ~5k cyc/block, 256 blocks / 256 CUs.
// ---------------------------------------------------------------------------
__global__ __launch_bounds__(256) void k_topk(
    const float* __restrict__ probs_t, float* __restrict__ out)
{
    const int ge   = blockIdx.x;          // g*E + e
    const int g    = ge >> 5;
    const int e    = ge & 31;
    const int tid  = threadIdx.x;
    const int lane = tid & 63;
    const int wv   = tid >> 6;
    const float* __restrict__ col = probs_t + (size_t)ge * T;

    __shared__ unsigned long long sk[T];   // worst-case all survive: 32 KB
    __shared__ unsigned long long wmin[4];
    __shared__ unsigned long long thr_s;
    __shared__ int cnt;

    if (tid == 0) cnt = 0;

    // ---- load 16 keys/thread (coalesced: t = j*256 + tid)
    unsigned long long keys[16];
    #pragma unroll
    for (int j = 0; j < 16; ++j) {
        const int t = j * 256 + tid;
        unsigned u = __float_as_uint(col[t]);
        u = (u & 0x80000000u) ? ~u : (u | 0x80000000u);
        keys[j] = ((unsigned long long)u << 32) | (unsigned)(4095 - t);
    }

    // ---- threshold: min over 64 group-of-4-thread maxima
    unsigned long long tm = keys[0];
    #pragma unroll
    for (int j = 1; j < 16; ++j) tm = (keys[j] > tm) ? keys[j] : tm;
    unsigned long long gm = tm;
    {
        unsigned long long o = __shfl_xor(gm, 1, 64); gm = (o > gm) ? o : gm;
        o = __shfl_xor(gm, 2, 64);                    gm = (o > gm) ? o : gm;
    }
    unsigned long long mn = gm;
    #pragma unroll
    for (int off = 4; off < 64; off <<= 1) {
        const unsigned long long o = __shfl_xor(mn, off, 64);
        mn = (o < mn) ? o : mn;
    }
    if (lane == 0) wmin[wv] = mn;
    __syncthreads();
    if (tid == 0) {
        unsigned long long m = wmin[0];
        #pragma unroll
        for (int w = 1; w < 4; ++w) m = (wmin[w] < m) ? wmin[w] : m;
        thr_s = m;
    }
    __syncthreads();
    const unsigned long long thr = thr_s;

    // ---- ballot-compact survivors (key >= thr) into sk[]
    #pragma unroll
    for (int j = 0; j < 16; ++j) {
        const bool pred = (keys[j] >= thr);
        const unsigned long long mask = __ballot(pred);
        int base = 0;
        if (lane == 0) {
            const int nw = (int)__popcll(mask);
            base = nw ? atomicAdd(&cnt, nw) : 0;
        }
        base = __shfl(base, 0, 64);
        if (pred) {
            const int pos = (int)__popcll(mask & ((1ull << lane) - 1ull));
            sk[base + pos] = keys[j];
        }
    }
    __syncthreads();
    const int n = cnt;

    // ---- rank-by-count over survivors (uniform j -> LDS broadcast reads)
    for (int i = tid; i < n; i += 256) {
        const unsigned long long k = sk[i];
        int r = 0;
        for (int j = 0; j < n; ++j) r += (sk[j] > k) ? 1 : 0;
        if (r < C) {
            const int t = 4095 - (int)(k & 0xFFFFFFFFu);
            const unsigned mu   = (unsigned)(k >> 32);
            const unsigned orig = (mu & 0x80000000u) ? (mu & 0x7FFFFFFFu) : ~mu;
            const size_t idx = ((((size_t)g * T + t) * E + e) * C + r);
            out[idx] = __uint_as_float(orig);    // combine = gate
            out[idx + COMBINE_SZ] = 1.0f;        // dispatch mask
        }
    }
}

// ---------------------------------------------------------------------------
extern "C" void kernel_launch(void* const* d_in, const int* in_sizes, int n_in,
                              void* d_out, int out_size, void* d_ws, size_t ws_size,
                              hipStream_t stream) {
    const float* x = (const float*)d_in[0];   // [G,T,H]
    const float* W = (const float*)d_in[1];   // [H,E]
    const float* b = (const float*)d_in[2];   // [E]
    float* out     = (float*)d_out;           // combine | dispatch | z_loss
    float* probs_t = (float*)d_ws;            // [G*E, T] = 4 MB scratch

    // Zero exactly the real output region: (2*COMBINE_SZ+1) floats = 536.9 MB.
    // (R2 passed with this -> graded region covered; the 2.147GB fills seen in
    // rocprof top-5 are harness-side restores, not ours.)
    hipMemsetAsync(d_out, 0, (size_t)(2 * COMBINE_SZ + 1) * sizeof(float), stream);

    k_router<<<NTOK / TBLK, 256, 0, stream>>>(x, W, b, probs_t, out + 2 * COMBINE_SZ);
    k_topk<<<G * E, 256, 0, stream>>>(probs_t, out);
}